// Round 3
// baseline (8366.435 us; speedup 1.0000x reference)
//
#include <hip/hip_runtime.h>
#include <math.h>

#define HIDDEN 1024
#define HEADS 16
#define HDIM 64
#define BATCH 2
#define SEQ 2048
#define NEGV -1.0e9f
#define TOK (BATCH * SEQ * HIDDEN)            // 4,194,304
#define SC_N ((size_t)BATCH * HEADS * SEQ * SEQ)  // 134,217,728
// score rows >= R0 are produced by the fixup kernel; (b*16+h) >= 29 <=> b=1,h>=13
#define ROW_CUT 29

// ---------------- GEMM: C[M,N] = A[M,K] @ B[K,N] + bias[N], fp32
__global__ __launch_bounds__(256) void gemm_bias(const float* __restrict__ A,
    const float* __restrict__ Bw, const float* __restrict__ bias,
    float* __restrict__ C, int M, int N, int K)
{
    __shared__ float As[64][17];
    __shared__ float Bs[16][65];
    int tid = threadIdx.x;
    int tx = tid & 15, ty = tid >> 4;
    int mBase = blockIdx.y * 64, nBase = blockIdx.x * 64;
    float acc[4][4] = {};
    int idA = tid * 4;
    int ra = idA >> 4, ca = idA & 15;   // A tile 64x16
    int rb = idA >> 6, cb = idA & 63;   // B tile 16x64
    int ty4 = ty * 4, tx4 = tx * 4;
    for (int k0 = 0; k0 < K; k0 += 16) {
        float4 fa = *(const float4*)(A + (size_t)(mBase + ra) * K + k0 + ca);
        As[ra][ca + 0] = fa.x; As[ra][ca + 1] = fa.y;
        As[ra][ca + 2] = fa.z; As[ra][ca + 3] = fa.w;
        float4 fb = *(const float4*)(Bw + (size_t)(k0 + rb) * N + nBase + cb);
        Bs[rb][cb + 0] = fb.x; Bs[rb][cb + 1] = fb.y;
        Bs[rb][cb + 2] = fb.z; Bs[rb][cb + 3] = fb.w;
        __syncthreads();
        #pragma unroll
        for (int kk = 0; kk < 16; kk++) {
            float a0 = As[ty4 + 0][kk], a1 = As[ty4 + 1][kk];
            float a2 = As[ty4 + 2][kk], a3 = As[ty4 + 3][kk];
            float b0 = Bs[kk][tx4 + 0], b1 = Bs[kk][tx4 + 1];
            float b2 = Bs[kk][tx4 + 2], b3 = Bs[kk][tx4 + 3];
            acc[0][0] += a0 * b0; acc[0][1] += a0 * b1; acc[0][2] += a0 * b2; acc[0][3] += a0 * b3;
            acc[1][0] += a1 * b0; acc[1][1] += a1 * b1; acc[1][2] += a1 * b2; acc[1][3] += a1 * b3;
            acc[2][0] += a2 * b0; acc[2][1] += a2 * b1; acc[2][2] += a2 * b2; acc[2][3] += a2 * b3;
            acc[3][0] += a3 * b0; acc[3][1] += a3 * b1; acc[3][2] += a3 * b2; acc[3][3] += a3 * b3;
        }
        __syncthreads();
    }
    #pragma unroll
    for (int i = 0; i < 4; i++) {
        int m = mBase + ty4 + i;
        #pragma unroll
        for (int j = 0; j < 4; j++) {
            int n = nBase + tx4 + j;
            C[(size_t)m * N + n] = acc[i][j] + bias[n];
        }
    }
}

// ---------------- Attention: one block per (b, h, q-row). Q in chunk0, K/V in score-tail
// scratch, ctx -> Cs. Scores written ONLY for rows (b*16+h) < ROW_CUT (rest via fixup).
__global__ __launch_bounds__(256) void attn_kernel(
    const float* __restrict__ qb, const float* __restrict__ kb, const float* __restrict__ vb,
    const int* __restrict__ mask, float* __restrict__ scores_out, float* __restrict__ ctx)
{
    __shared__ float qs[HDIM];
    __shared__ float sc[SEQ];
    __shared__ float red[4];
    __shared__ float part[4][HDIM];
    int tid = threadIdx.x;
    int q = blockIdx.x, h = blockIdx.y, b = blockIdx.z;
    bool wr = (b * HEADS + h) < ROW_CUT;

    if (tid < HDIM)
        qs[tid] = qb[((size_t)(b * SEQ + q)) * HIDDEN + h * HDIM + tid];
    __syncthreads();

    const int* mrow = mask + ((size_t)(b * SEQ + q)) * SEQ;
    const float* kbase = kb + (size_t)b * SEQ * HIDDEN + h * HDIM;
    float* srow = scores_out + (((size_t)(b * HEADS + h)) * SEQ + q) * SEQ;

    float lmax = -3.0e38f;
    for (int j = tid; j < SEQ; j += 256) {
        const float4* kp = (const float4*)(kbase + (size_t)j * HIDDEN);
        float dot = 0.f;
        #pragma unroll
        for (int c = 0; c < 16; c++) {
            float4 u = kp[c];
            dot += qs[c * 4 + 0] * u.x + qs[c * 4 + 1] * u.y
                 + qs[c * 4 + 2] * u.z + qs[c * 4 + 3] * u.w;
        }
        float s = (mrow[j] == 0) ? NEGV : dot * 0.125f;
        sc[j] = s;
        if (wr) srow[j] = s;
        lmax = fmaxf(lmax, s);
    }
    #pragma unroll
    for (int o = 32; o > 0; o >>= 1) lmax = fmaxf(lmax, __shfl_xor(lmax, o, 64));
    __syncthreads();
    if ((tid & 63) == 0) red[tid >> 6] = lmax;
    __syncthreads();
    float m = fmaxf(fmaxf(red[0], red[1]), fmaxf(red[2], red[3]));

    float lsum = 0.f;
    for (int j = tid; j < SEQ; j += 256) {
        float e = __expf(sc[j] - m);
        sc[j] = e;
        lsum += e;
    }
    #pragma unroll
    for (int o = 32; o > 0; o >>= 1) lsum += __shfl_xor(lsum, o, 64);
    __syncthreads();
    if ((tid & 63) == 0) red[tid >> 6] = lsum;
    __syncthreads();
    float inv = 1.0f / (red[0] + red[1] + red[2] + red[3]);

    int d = tid & 63, chunk = tid >> 6;
    const float* vbase = vb + (size_t)b * SEQ * HIDDEN + h * HDIM + d;
    float acc = 0.f;
    int j0 = chunk * 512;
    for (int j = j0; j < j0 + 512; j++)
        acc += sc[j] * vbase[(size_t)j * HIDDEN];
    part[chunk][d] = acc;
    __syncthreads();
    if (tid < HDIM) {
        float r = (part[0][tid] + part[1][tid] + part[2][tid] + part[3][tid]) * inv;
        ctx[((size_t)(b * SEQ + q)) * HIDDEN + h * HDIM + tid] = r;
    }
}

// ---------------- Residual + LayerNorm, in place over chunk0 (h -> out)
__global__ __launch_bounds__(256) void ln_kernel(float* __restrict__ hbuf,
    const float* __restrict__ x, const float* __restrict__ g, const float* __restrict__ bb,
    float* __restrict__ out)
{
    __shared__ float red[4];
    int row = blockIdx.x, tid = threadIdx.x;
    size_t base = (size_t)row * HIDDEN + tid * 4;
    float4 fh = *(const float4*)(hbuf + base);
    float4 fx = *(const float4*)(x + base);
    float y0 = fh.x + fx.x, y1 = fh.y + fx.y, y2 = fh.z + fx.z, y3 = fh.w + fx.w;

    float s = y0 + y1 + y2 + y3;
    #pragma unroll
    for (int o = 32; o > 0; o >>= 1) s += __shfl_xor(s, o, 64);
    if ((tid & 63) == 0) red[tid >> 6] = s;
    __syncthreads();
    float mu = (red[0] + red[1] + red[2] + red[3]) * (1.f / 1024.f);

    float d0 = y0 - mu, d1 = y1 - mu, d2 = y2 - mu, d3 = y3 - mu;
    float sq = d0 * d0 + d1 * d1 + d2 * d2 + d3 * d3;
    #pragma unroll
    for (int o = 32; o > 0; o >>= 1) sq += __shfl_xor(sq, o, 64);
    __syncthreads();
    if ((tid & 63) == 0) red[tid >> 6] = sq;
    __syncthreads();
    float var = (red[0] + red[1] + red[2] + red[3]) * (1.f / 1024.f);
    float r = rsqrtf(var + 1e-12f);

    float4 fg = *(const float4*)(g + tid * 4);
    float4 fb = *(const float4*)(bb + tid * 4);
    float4 o4;
    o4.x = d0 * r * fg.x + fb.x;
    o4.y = d1 * r * fg.y + fb.y;
    o4.z = d2 * r * fg.z + fb.z;
    o4.w = d3 * r * fg.w + fb.w;
    *(float4*)(out + base) = o4;
}

// ---------------- Score fixup: recompute q,k from x,W for (b=1, h=13..15) tiles and
// write the tail score rows (overwrites the dead K/V/ctx scratch). Runs LAST.
__global__ __launch_bounds__(256) void score_fixup(const float* __restrict__ x,
    const float* __restrict__ Wq, const float* __restrict__ bq,
    const float* __restrict__ Wk, const float* __restrict__ bk,
    const int* __restrict__ mask, float* __restrict__ scores)
{
    __shared__ float As[64][17];
    __shared__ float Bs[16][65];
    __shared__ float qt[64][65];
    __shared__ float kt[64][65];
    const int b = 1;
    int h = 13 + blockIdx.z;
    int qBase = blockIdx.y * 64, kkBase = blockIdx.x * 64;
    int hcol = h * HDIM;
    int tid = threadIdx.x;
    int tx = tid & 15, ty = tid >> 4;
    int ty4 = ty * 4, tx4 = tx * 4;
    int idA = tid * 4;
    int ra = idA >> 4, ca = idA & 15;
    int rb = idA >> 6, cb = idA & 63;

    for (int pass = 0; pass < 2; pass++) {
        int rowBase = b * SEQ + (pass ? kkBase : qBase);
        const float* W = pass ? Wk : Wq;
        const float* bias = pass ? bk : bq;
        float acc[4][4] = {};
        for (int k0 = 0; k0 < HIDDEN; k0 += 16) {
            float4 fa = *(const float4*)(x + (size_t)(rowBase + ra) * HIDDEN + k0 + ca);
            As[ra][ca + 0] = fa.x; As[ra][ca + 1] = fa.y;
            As[ra][ca + 2] = fa.z; As[ra][ca + 3] = fa.w;
            float4 fb = *(const float4*)(W + (size_t)(k0 + rb) * HIDDEN + hcol + cb);
            Bs[rb][cb + 0] = fb.x; Bs[rb][cb + 1] = fb.y;
            Bs[rb][cb + 2] = fb.z; Bs[rb][cb + 3] = fb.w;
            __syncthreads();
            #pragma unroll
            for (int kk = 0; kk < 16; kk++) {
                float a0 = As[ty4 + 0][kk], a1 = As[ty4 + 1][kk];
                float a2 = As[ty4 + 2][kk], a3 = As[ty4 + 3][kk];
                float b0 = Bs[kk][tx4 + 0], b1 = Bs[kk][tx4 + 1];
                float b2 = Bs[kk][tx4 + 2], b3 = Bs[kk][tx4 + 3];
                acc[0][0] += a0 * b0; acc[0][1] += a0 * b1; acc[0][2] += a0 * b2; acc[0][3] += a0 * b3;
                acc[1][0] += a1 * b0; acc[1][1] += a1 * b1; acc[1][2] += a1 * b2; acc[1][3] += a1 * b3;
                acc[2][0] += a2 * b0; acc[2][1] += a2 * b1; acc[2][2] += a2 * b2; acc[2][3] += a2 * b3;
                acc[3][0] += a3 * b0; acc[3][1] += a3 * b1; acc[3][2] += a3 * b2; acc[3][3] += a3 * b3;
            }
            __syncthreads();
        }
        #pragma unroll
        for (int i = 0; i < 4; i++)
            #pragma unroll
            for (int j = 0; j < 4; j++) {
                float v = acc[i][j] + bias[hcol + tx4 + j];
                if (pass) kt[ty4 + i][tx4 + j] = v;
                else      qt[ty4 + i][tx4 + j] = v;
            }
        __syncthreads();
    }

    float s[4][4] = {};
    for (int d = 0; d < HDIM; d++) {
        float qv0 = qt[ty4 + 0][d], qv1 = qt[ty4 + 1][d];
        float qv2 = qt[ty4 + 2][d], qv3 = qt[ty4 + 3][d];
        float kv0 = kt[tx4 + 0][d], kv1 = kt[tx4 + 1][d];
        float kv2 = kt[tx4 + 2][d], kv3 = kt[tx4 + 3][d];
        s[0][0] += qv0 * kv0; s[0][1] += qv0 * kv1; s[0][2] += qv0 * kv2; s[0][3] += qv0 * kv3;
        s[1][0] += qv1 * kv0; s[1][1] += qv1 * kv1; s[1][2] += qv1 * kv2; s[1][3] += qv1 * kv3;
        s[2][0] += qv2 * kv0; s[2][1] += qv2 * kv1; s[2][2] += qv2 * kv2; s[2][3] += qv2 * kv3;
        s[3][0] += qv3 * kv0; s[3][1] += qv3 * kv1; s[3][2] += qv3 * kv2; s[3][3] += qv3 * kv3;
    }
    #pragma unroll
    for (int i = 0; i < 4; i++) {
        int q = qBase + ty4 + i;
        const int* mrow = mask + ((size_t)(b * SEQ + q)) * SEQ;
        float* srow = scores + (((size_t)(b * HEADS + h)) * SEQ + q) * SEQ;
        #pragma unroll
        for (int j = 0; j < 4; j++) {
            int kk = kkBase + tx4 + j;
            srow[kk] = (mrow[kk] == 0) ? NEGV : s[i][j] * 0.125f;
        }
    }
}

extern "C" void kernel_launch(void* const* d_in, const int* in_sizes, int n_in,
                              void* d_out, int out_size, void* d_ws, size_t ws_size,
                              hipStream_t stream)
{
    const float* x   = (const float*)d_in[0];
    const int*   msk = (const int*)d_in[1];
    const float* Wq  = (const float*)d_in[2];
    const float* bq  = (const float*)d_in[3];
    const float* Wk  = (const float*)d_in[4];
    const float* bk  = (const float*)d_in[5];
    const float* Wv  = (const float*)d_in[6];
    const float* bv  = (const float*)d_in[7];
    const float* Wo  = (const float*)d_in[8];
    const float* bo  = (const float*)d_in[9];
    const float* lng = (const float*)d_in[10];
    const float* lnb = (const float*)d_in[11];

    float* out0   = (float*)d_out;                 // chunk 0: [B*S, HIDDEN]
    float* scores = out0 + (size_t)TOK;            // chunk 1: [B,H,S,S]

    // Scratch carved from the TAIL of the score region (rows b=1,h>=13, written by fixup last)
    float* Ks  = scores + (SC_N - (size_t)3 * TOK);
    float* Vs  = Ks + TOK;
    float* Cs  = Vs + TOK;
    float* Qs  = out0;   // Q staged in chunk0; overwritten by h after attention

    const int M = BATCH * SEQ;
    dim3 gg(HIDDEN / 64, M / 64);
    gemm_bias<<<gg, 256, 0, stream>>>(x, Wq, bq, Qs, M, HIDDEN, HIDDEN);
    gemm_bias<<<gg, 256, 0, stream>>>(x, Wk, bk, Ks, M, HIDDEN, HIDDEN);
    gemm_bias<<<gg, 256, 0, stream>>>(x, Wv, bv, Vs, M, HIDDEN, HIDDEN);
    attn_kernel<<<dim3(SEQ, HEADS, BATCH), 256, 0, stream>>>(Qs, Ks, Vs, msk, scores, Cs);
    gemm_bias<<<gg, 256, 0, stream>>>(Cs, Wo, bo, out0, M, HIDDEN, HIDDEN);  // h -> chunk0
    ln_kernel<<<M, 256, 0, stream>>>(out0, x, lng, lnb, out0);
    score_fixup<<<dim3(SEQ / 64, SEQ / 64, 3), 256, 0, stream>>>(x, Wq, bq, Wk, bk, msk, scores);
}